// Round 7
// baseline (68.390 us; speedup 1.0000x reference)
//
#include <hip/hip_runtime.h>

#define HH 1024
#define WW 1024
#define NPIX (HH*WW)
#define NG 16           // col-max groups per sample (64 rows each)
#define EPSF 1e-8f
#define AGENT __HIP_MEMORY_SCOPE_AGENT

__device__ inline float wrsum(float v){ for(int o=32;o;o>>=1) v += __shfl_down(v,o); return v; }
__device__ inline float wrmin(float v){ for(int o=32;o;o>>=1) v = fminf(v,__shfl_down(v,o)); return v; }
__device__ inline float wrmax(float v){ for(int o=32;o;o>>=1) v = fmaxf(v,__shfl_down(v,o)); return v; }

// ---- Kernel 1 (the ONLY full-data pass) ----
// Grid = B*16. Block = (sample s, group g of 64 rows = 4 chunks of 16).
// Thread t owns cols 4t..4t+3. Outputs: per-(s,row) {max,min,sum};
// per-(s,g,col) max (plain writes); per-(s,g) {sabs,cnt,sxx}. Zeroes ctr.
__global__ __launch_bounds__(256) void k_main(const float* __restrict__ x,
    float* __restrict__ RM, float* __restrict__ RMn, float* __restrict__ RS,
    float* __restrict__ CM, float* __restrict__ p1, int* __restrict__ ctr){
  int s = blockIdx.x >> 4, g = blockIdx.x & 15;
  int t = threadIdx.x;
  if(blockIdx.x==0 && t==0) *ctr = 0;
  int wid = t>>6, lane = t&63;
  float sabs=0.f, cnt=0.f, sxx=0.f;
  float cm4[4]={-INFINITY,-INFINITY,-INFINITY,-INFINITY};
  __shared__ float sred[3][4];
  __shared__ float rowm[4][16], rown[4][16], rowsu[4][16];

  for(int c=0;c<4;c++){
    const float4* xp = (const float4*)(x + (size_t)s*NPIX + ((size_t)g*64 + c*16)*WW);
    float rm[16], rn[16], rs[16];
    #pragma unroll
    for(int r=0;r<16;r++){
      float4 v = xp[r*256 + t];
      float a[4]={v.x,v.y,v.z,v.w};
      float rmx=-INFINITY, rmn=INFINITY, rsu=0.f;
      #pragma unroll
      for(int j=0;j<4;j++){
        float xx = a[j];
        rmx = fmaxf(rmx, xx); rmn = fminf(rmn, xx); rsu += xx;
        cm4[j] = fmaxf(cm4[j], xx);
        sxx = fmaf(xx, xx, sxx);
        float e = __expf(fabsf(xx));        // |sigmoid(x)-0.5| = 0.5 - 1/(1+e^{|x|})
        sabs += 0.5f - 1.f/(1.f + e);
        cnt += (xx > 0.f) ? 1.f : 0.f;      // sigmoid(x)>0.5 <=> x>0
      }
      rm[r]=rmx; rn[r]=rmn; rs[r]=rsu;
    }
    #pragma unroll
    for(int r=0;r<16;r++){
      float a = wrmax(rm[r]), b = wrmin(rn[r]), cc = wrsum(rs[r]);
      if(lane==0){ rowm[wid][r]=a; rown[wid][r]=b; rowsu[wid][r]=cc; }
    }
    __syncthreads();
    if(t<16){
      size_t ri = (size_t)s*HH + (size_t)g*64 + c*16 + t;
      RM [ri] = fmaxf(fmaxf(rowm[0][t],rowm[1][t]), fmaxf(rowm[2][t],rowm[3][t]));
      RMn[ri] = fminf(fminf(rown[0][t],rown[1][t]), fminf(rown[2][t],rown[3][t]));
      RS [ri] = rowsu[0][t]+rowsu[1][t]+rowsu[2][t]+rowsu[3][t];
    }
    __syncthreads();   // shared arrays reused next chunk
  }
  // per-(s,g) column-max: plain coalesced float4 store (2 MB total)
  *(float4*)(CM + ((size_t)s*NG + g)*WW + 4*t) = make_float4(cm4[0],cm4[1],cm4[2],cm4[3]);

  sabs = wrsum(sabs); cnt = wrsum(cnt); sxx = wrsum(sxx);
  if(lane==0){ sred[0][wid]=sabs; sred[1][wid]=cnt; sred[2][wid]=sxx; }
  __syncthreads();
  if(t==0){
    float* o = p1 + ((size_t)s*NG + g)*3;
    o[0] = sred[0][0]+sred[0][1]+sred[0][2]+sred[0][3];
    o[1] = sred[1][0]+sred[1][1]+sred[1][2]+sred[1][3];
    o[2] = sred[2][0]+sred[2][1]+sred[2][2]+sred[2][3];
  }
}

// ---- Kernel 2: per-sample everything + last-block global combine ----
__global__ __launch_bounds__(256) void k_sample(const float* __restrict__ x,
    const float* __restrict__ RM, const float* __restrict__ RMn,
    const float* __restrict__ RS, const float* __restrict__ CM,
    const float* __restrict__ p1, float* __restrict__ lossV, float* __restrict__ valV,
    int* __restrict__ ctr, float* __restrict__ out, int B){
  int s = blockIdx.x, t = threadIdx.x;
  int wid = t>>6, lane = t&63;
  __shared__ float bc[6];
  __shared__ float lred[3][4];
  __shared__ int ext[4];
  // Phase A: vmin/vmax/sx from row arrays; sabs/cnt/sxx from p1
  float vmax=-INFINITY, vmin=INFINITY, sx=0.f;
  #pragma unroll
  for(int i=0;i<4;i++){
    size_t ri = (size_t)s*HH + 4*t + i;
    vmax = fmaxf(vmax, RM[ri]); vmin = fminf(vmin, RMn[ri]); sx += RS[ri];
  }
  vmax = wrmax(vmax); vmin = wrmin(vmin); sx = wrsum(sx);
  if(lane==0){ lred[0][wid]=vmax; lred[1][wid]=vmin; lred[2][wid]=sx; }
  float sabs=0.f, cnt=0.f, sxx=0.f;
  if(t<64){
    float a=0.f,b=0.f,c=0.f;
    if(t<NG){
      const float* o = p1 + ((size_t)s*NG + t)*3;
      a=o[0]; b=o[1]; c=o[2];
    }
    sabs=wrsum(a); cnt=wrsum(b); sxx=wrsum(c);
  }
  if(t==0){ ext[0]=0x7fffffff; ext[1]=-1; ext[2]=0x7fffffff; ext[3]=-1; }
  __syncthreads();
  if(t==0){
    float M = fmaxf(fmaxf(lred[0][0],lred[0][1]), fmaxf(lred[0][2],lred[0][3]));
    float m = fminf(fminf(lred[1][0],lred[1][1]), fminf(lred[1][2],lred[1][3]));
    float X = lred[2][0]+lred[2][1]+lred[2][2]+lred[2][3];
    float lo=m, d=M-m+EPSF, inv=1.f/d;
    float conf = sabs/(float)NPIX, area = cnt/(float)NPIX;
    float w = 0.4f;
    if(conf < 0.3f)  w *= 2.0f;
    if(area < 0.05f) w *= 1.5f;
    if(conf > 0.4f && area > 0.1f) w *= 0.5f;
    bc[0]=lo; bc[1]=inv; bc[2]=lo+0.5f*d; bc[3]=w;
    bc[4]=inv*inv*(sxx - 2.f*lo*X + (float)NPIX*lo*lo);
  }
  __syncthreads();
  float lo=bc[0], inv=bc[1], T=bc[2], w=bc[3], spn2=bc[4];
  // Phase B: extents. Cols: reduce CM over NG groups (thread t: cols 4t..4t+3)
  {
    const float4* cm = (const float4*)(CM + (size_t)s*NG*WW) + t;
    float4 mx = cm[0];
    #pragma unroll
    for(int g=1; g<NG; g++){
      float4 v = cm[(size_t)g*256];
      mx.x=fmaxf(mx.x,v.x); mx.y=fmaxf(mx.y,v.y);
      mx.z=fmaxf(mx.z,v.z); mx.w=fmaxf(mx.w,v.w);
    }
    float a4[4]={mx.x,mx.y,mx.z,mx.w};
    int clo=0x7fffffff, chi=-1, rlo=0x7fffffff, rhi=-1;
    #pragma unroll
    for(int i=0;i<4;i++){
      int c = 4*t+i;
      if(a4[i] > T){ clo=min(clo,c); chi=max(chi,c); }
      if(RM[(size_t)s*HH + c] > T){ rlo=min(rlo,c); rhi=max(rhi,c); }
    }
    if(chi>=0){ atomicMin(&ext[2],clo); atomicMax(&ext[3],chi); }
    if(rhi>=0){ atomicMin(&ext[0],rlo); atomicMax(&ext[1],rhi); }
  }
  __syncthreads();
  int r0=ext[0], r1=ext[1], c0=ext[2], c1=ext[3];
  // Phase C: rect sum & min
  float su=0.f, mi=INFINITY;
  if(r1 >= 0){
    if(c0==0 && c1==WW-1){           // full-width fast path (row arrays exact)
      #pragma unroll
      for(int i=0;i<4;i++){
        int r = 4*t+i;
        if(r>=r0 && r<=r1){
          size_t ri = (size_t)s*HH + r;
          su += RS[ri]; mi = fminf(mi, RMn[ri]);
        }
      }
    } else {                          // general fallback: direct x over rect
      for(int r=r0; r<=r1; r++){
        const float* xr = x + (size_t)s*NPIX + (size_t)r*WW;
        for(int c=c0+t; c<=c1; c+=256){ float v=xr[c]; su += v; mi = fminf(mi,v); }
      }
    }
  }
  su = wrsum(su); mi = wrmin(mi);
  __shared__ float l1[4], l2[4];
  if(lane==0){ l1[wid]=su; l2[wid]=mi; }
  __syncthreads();
  if(t==0){
    float S = l1[0]+l1[1]+l1[2]+l1[3];
    float Mn = fminf(fminf(l2[0],l2[1]), fminf(l2[2],l2[3]));
    float loss=0.f, val=0.f;
    if(r1 >= 0){
      float area = (float)((r1-r0+1)*(c1-c0+1));
      val = (Mn <= T) ? 1.f : 0.f;          // exists rect pixel not binary
      float srpn = inv*(S - area*lo);       // sum of pn over rect
      loss = ((spn2 - 2.f*srpn + area)/(float)NPIX) * w * val;
    }
    lossV[s]=loss; valV[s]=val;
    __threadfence();
    int old = __hip_atomic_fetch_add(ctr, 1, __ATOMIC_ACQ_REL, AGENT);
    if(old == B-1){
      __threadfence();
      float L=0.f, V=0.f;
      for(int ss=0; ss<B; ss++){            // fixed order -> deterministic
        L += __hip_atomic_load(&lossV[ss], __ATOMIC_RELAXED, AGENT);
        V += __hip_atomic_load(&valV[ss],  __ATOMIC_RELAXED, AGENT);
      }
      out[0] = (V > 0.f) ? (L / fmaxf(V, 1.f)) : 0.f;
    }
  }
}

extern "C" void kernel_launch(void* const* d_in, const int* in_sizes, int n_in,
                              void* d_out, int out_size, void* d_ws, size_t ws_size,
                              hipStream_t stream) {
  const float* x = (const float*)d_in[0];
  int B = in_sizes[0] / NPIX;   // 32
  char* ws = (char*)d_ws;
  float* CM    = (float*)(ws);                                 // B*16*1024*4 = 2 MB
  float* RM    = (float*)(ws + (size_t)2*1024*1024);           // 128 KB
  float* RMn   = (float*)(ws + (size_t)2*1024*1024 + 131072);
  float* RS    = (float*)(ws + (size_t)2*1024*1024 + 262144);
  float* p1    = (float*)(ws + (size_t)2*1024*1024 + 393216);  // 6 KB
  float* lossV = (float*)(ws + (size_t)2*1024*1024 + 401408);  // 128 B
  float* valV  = (float*)(ws + (size_t)2*1024*1024 + 401536);  // 128 B
  int*   ctr   = (int*)  (ws + (size_t)2*1024*1024 + 401664);  // 4 B
  float* out   = (float*)d_out;

  k_main  <<<B*NG, 256, 0, stream>>>(x, RM, RMn, RS, CM, p1, ctr);
  k_sample<<<B,    256, 0, stream>>>(x, RM, RMn, RS, CM, p1, lossV, valV, ctr, out, B);
}